// Round 6
// baseline (523.238 us; speedup 1.0000x reference)
//
#include <hip/hip_runtime.h>

constexpr int B_ = 16, L_ = 2048, C_ = 256, K_ = 64, INNER_ = 4096;
constexpr int NCH = 16;          // L-chunks
constexpr int RPB = 128;         // rows per k_em block
#define EPSF 1e-6f

typedef __attribute__((ext_vector_type(8)))  short bf16x8;
typedef __attribute__((ext_vector_type(4)))  float f32x4;
typedef __attribute__((ext_vector_type(16))) float f32x16;
typedef _Float16 f16;
typedef __attribute__((ext_vector_type(8))) _Float16 f16x8;
typedef __attribute__((ext_vector_type(4))) _Float16 f16x4;

__device__ __forceinline__ unsigned short f2bf(float f) {
  union { float f; unsigned u; } v; v.f = f;
  unsigned r = v.u + 0x7fffu + ((v.u >> 16) & 1u);   // RNE
  return (unsigned short)(r >> 16);
}

__device__ __forceinline__ void gload16(const void* src, void* lds) {
  __builtin_amdgcn_global_load_lds(
      (const __attribute__((address_space(1))) unsigned*)src,
      (__attribute__((address_space(3))) unsigned*)lds, 16, 0, 0);
}

// ---------------------------------------------------------------- k_pre
// w1bf = bf16(w1 * bn_scale_row); w2fr = bf16(w2) in GEMM2 A-frag order;
// bnshH; muF init.
__global__ __launch_bounds__(256) void k_pre(
    const float* __restrict__ w1, const float* __restrict__ w2,
    const float* __restrict__ gamma, const float* __restrict__ beta,
    const float* __restrict__ bmean, const float* __restrict__ bvar,
    const float* __restrict__ b1, const float* __restrict__ mu0,
    unsigned short* __restrict__ w1bf, unsigned short* __restrict__ w2fr,
    f16* __restrict__ bnshH, f16* __restrict__ muF)
{
  int i = blockIdx.x * 256 + threadIdx.x;     // covers 1048576
  if (i < INNER_ * C_) {
    int r = i >> 8;
    float sc = gamma[r] * rsqrtf(bvar[r] + 1e-5f);
    w1bf[i] = f2bf(w1[i] * sc);
    // w2fr: A-frag order for 32x32x16: f = ((ks*2+l5)*8 + w)*256 + l31*8 + j
    int j = i & 7, l31 = (i >> 3) & 31, w = (i >> 8) & 7, l5 = (i >> 11) & 1, ks = i >> 12;
    int ii = ks * 16 + l5 * 8 + j;
    int o  = w * 32 + l31;
    w2fr[i] = f2bf(w2[(size_t)o * INNER_ + ii]);
  }
  if (i < B_ * K_ * C_) muF[i] = (f16)mu0[i & (K_ * C_ - 1)];
  if (i < INNER_) {
    float sc = gamma[i] * rsqrtf(bvar[i] + 1e-5f);
    bnshH[i] = (f16)fmaf(b1[i] - bmean[i], sc, beta[i]);
  }
}

// ---------------------------------------------------------------- k_xT
// x [B][L][C] f32 -> xf f16 [B][L][C] + xTf f16 [B][C][L]
__global__ __launch_bounds__(256) void k_xT(const float* __restrict__ x,
                                            f16* __restrict__ xf, f16* __restrict__ xTf)
{
  __shared__ float ts[64][65];
  int l0 = blockIdx.x * 64, c0 = blockIdx.y * 64, b = blockIdx.z;
  int t = threadIdx.x;
  for (int p = 0; p < 16; ++p) {
    int e = t + p * 256, i = e >> 6, j = e & 63;
    float vv = x[((size_t)b * L_ + l0 + i) * C_ + c0 + j];
    ts[i][j] = vv;
    xf[((size_t)b * L_ + l0 + i) * C_ + c0 + j] = (f16)vv;
  }
  __syncthreads();
  for (int p = 0; p < 16; ++p) {
    int e = t + p * 256, i = e >> 6, j = e & 63;
    xTf[((size_t)b * C_ + c0 + i) * L_ + l0 + j] = (f16)ts[j][i];
  }
}

// ---------------------------------------------------------------- k_em
// (unchanged from r5 — validated)
template<bool DO_MU, bool WRITE_Z>
__global__ __launch_bounds__(512, 2) void k_em(
    const f16* __restrict__ xf,    // [B][L][C]
    const f16* __restrict__ xTf,   // [B][C][L]
    const f16* __restrict__ muF,   // [B][K][C]
    f16* __restrict__ zout,        // [B][L][K]
    float* __restrict__ cp,        // [NCH][B*K]
    f16* __restrict__ part)        // [NCH][B][K][C]
{
  __shared__ f16 mu_s[K_ * C_];     // 32KB, slot ^ (k&15)
  __shared__ f16 zT_s[K_ * RPB];    // 16KB, slot ^ (k&15)
  __shared__ f16 xtile[C_ * RPB];   // 64KB, slot ^ (c&7)
  __shared__ float cpart[8][K_];

  int t = threadIdx.x, b = blockIdx.y, chn = blockIdx.x, l0 = chn * RPB;
  int w = t >> 6, lane = t & 63, l15 = lane & 15, g = lane >> 4;

#pragma unroll
  for (int q = 0; q < 4; ++q) {
    int s = q * 512 + t, k = s >> 5, sl = s & 31;
    gload16(muF + (size_t)b * (K_ * C_) + k * C_ + ((sl ^ (k & 15)) << 3), mu_s + s * 8);
  }
  __builtin_amdgcn_sched_barrier(0);
  f16x8 xfr[8];
  const f16* xr = xf + ((size_t)b * L_ + l0 + w * 16 + l15) * C_ + g * 8;
#pragma unroll
  for (int ck = 0; ck < 8; ++ck) xfr[ck] = *(const f16x8*)(xr + ck * 32);
  __builtin_amdgcn_sched_barrier(0);
  if (DO_MU) {
#pragma unroll
    for (int q = 0; q < 8; ++q) {
      int s = q * 512 + t, c = s >> 4, sl = s & 15;
      gload16(xTf + (size_t)(b * C_ + c) * L_ + l0 + ((sl ^ (c & 7)) << 3), xtile + s * 8);
    }
    __builtin_amdgcn_sched_barrier(0);
    asm volatile("s_waitcnt vmcnt(16)" ::: "memory");
  } else {
    asm volatile("s_waitcnt vmcnt(8)" ::: "memory");
  }
  __builtin_amdgcn_s_barrier();
  __builtin_amdgcn_sched_barrier(0);

  f32x4 acc[4];
#pragma unroll
  for (int mt = 0; mt < 4; ++mt)
#pragma unroll
    for (int j = 0; j < 4; ++j) acc[mt][j] = 0.f;
#pragma unroll
  for (int ck = 0; ck < 8; ++ck) {
#pragma unroll
    for (int mt = 0; mt < 4; ++mt) {
      f16x8 a = *(const f16x8*)(mu_s + (mt * 16 + l15) * C_ + (((ck * 4 + g) ^ l15) << 3));
      acc[mt] = __builtin_amdgcn_mfma_f32_16x16x32_f16(a, xfr[ck], acc[mt], 0, 0, 0);
    }
  }

  float z[4][4];
  {
    float mx = acc[0][0];
#pragma unroll
    for (int mt = 0; mt < 4; ++mt)
#pragma unroll
      for (int jj = 0; jj < 4; ++jj) mx = fmaxf(mx, acc[mt][jj]);
    mx = fmaxf(mx, __shfl_xor(mx, 16, 64));
    mx = fmaxf(mx, __shfl_xor(mx, 32, 64));
    float sm = 0.f;
#pragma unroll
    for (int mt = 0; mt < 4; ++mt)
#pragma unroll
      for (int jj = 0; jj < 4; ++jj) {
        float e = __expf(acc[mt][jj] - mx);
        z[mt][jj] = e; sm += e;
      }
    sm += __shfl_xor(sm, 16, 64);
    sm += __shfl_xor(sm, 32, 64);
    float inv = 1.f / sm;
#pragma unroll
    for (int mt = 0; mt < 4; ++mt)
#pragma unroll
      for (int jj = 0; jj < 4; ++jj) z[mt][jj] *= inv;
  }

#pragma unroll
  for (int mt = 0; mt < 4; ++mt)
#pragma unroll
    for (int jj = 0; jj < 4; ++jj) {
      float v = z[mt][jj];
      v += __shfl_xor(v, 1, 64); v += __shfl_xor(v, 2, 64);
      v += __shfl_xor(v, 4, 64); v += __shfl_xor(v, 8, 64);
      if (l15 == 0) cpart[w][mt * 16 + g * 4 + jj] = v;
    }

#pragma unroll
  for (int mt = 0; mt < 4; ++mt)
#pragma unroll
    for (int jj = 0; jj < 4; ++jj) {
      int k = mt * 16 + g * 4 + jj;
      int tl = w * 16 + l15;
      f16 h = (f16)z[mt][jj];
      if (DO_MU)   zT_s[k * RPB + (((tl >> 3) ^ (k & 15)) << 3) + (tl & 7)] = h;
      if (WRITE_Z) zout[((size_t)b * L_ + l0 + tl) * K_ + k] = h;
    }
  __syncthreads();

  if (t < K_) {
    float s = 0.f;
#pragma unroll
    for (int q = 0; q < 8; ++q) s += cpart[q][t];
    cp[(size_t)chn * (B_ * K_) + b * K_ + t] = s;
  }

  if (DO_MU) {
    f32x4 a3[4][2];
#pragma unroll
    for (int mt = 0; mt < 4; ++mt)
#pragma unroll
      for (int nt = 0; nt < 2; ++nt)
#pragma unroll
        for (int j = 0; j < 4; ++j) a3[mt][nt][j] = 0.f;
    int cb = w * 32;
#pragma unroll
    for (int ks = 0; ks < 4; ++ks) {
      f16x8 az[4], bx[2];
#pragma unroll
      for (int mt = 0; mt < 4; ++mt)
        az[mt] = *(const f16x8*)(zT_s + (mt * 16 + l15) * RPB + (((ks * 4 + g) ^ l15) << 3));
#pragma unroll
      for (int nt = 0; nt < 2; ++nt) {
        int c = cb + nt * 16 + l15;
        bx[nt] = *(const f16x8*)(xtile + c * RPB + (((ks * 4 + g) ^ (c & 7)) << 3));
      }
#pragma unroll
      for (int mt = 0; mt < 4; ++mt)
#pragma unroll
        for (int nt = 0; nt < 2; ++nt)
          a3[mt][nt] = __builtin_amdgcn_mfma_f32_16x16x32_f16(az[mt], bx[nt], a3[mt][nt], 0, 0, 0);
    }
    f16* pp = part + (((size_t)chn * B_ + b) * K_) * C_;
#pragma unroll
    for (int mt = 0; mt < 4; ++mt)
#pragma unroll
      for (int nt = 0; nt < 2; ++nt)
#pragma unroll
        for (int jj = 0; jj < 4; ++jj)
          pp[(size_t)(mt * 16 + g * 4 + jj) * C_ + cb + nt * 16 + l15] = (f16)a3[mt][nt][jj];
  }
}

// ---------------------------------------------------------------- k_mufin
template<bool LAST>
__global__ __launch_bounds__(256) void k_mufin(
    const f16* __restrict__ part, const float* __restrict__ cp,
    f16* __restrict__ muF, f16* __restrict__ muT,
    float* __restrict__ zsA, float* __restrict__ outmu)
{
  int b = blockIdx.x >> 4, kg = blockIdx.x & 15, t = threadIdx.x;
  int kr = t >> 6, c4 = t & 63, k = kg * 4 + kr;
  float a0 = 0.f, a1 = 0.f, a2 = 0.f, a3 = 0.f;
#pragma unroll
  for (int chn = 0; chn < NCH; ++chn) {
    f16x4 p = *(const f16x4*)(part + (((size_t)chn * B_ + b) * K_ + k) * C_ + c4 * 4);
    a0 += (float)p[0]; a1 += (float)p[1]; a2 += (float)p[2]; a3 += (float)p[3];
  }
  float zs = 0.f;
#pragma unroll
  for (int chn = 0; chn < NCH; ++chn) zs += cp[(size_t)chn * (B_ * K_) + b * K_ + k];
  float sc = 1.f / (EPSF + zs);
  a0 *= sc; a1 *= sc; a2 *= sc; a3 *= sc;
  float ssq = a0 * a0 + a1 * a1 + a2 * a2 + a3 * a3;
#pragma unroll
  for (int off = 32; off >= 1; off >>= 1) ssq += __shfl_xor(ssq, off, 64);
  float inv = 1.f / (EPSF + sqrtf(ssq));
  a0 *= inv; a1 *= inv; a2 *= inv; a3 *= inv;
  size_t base = (size_t)(b * K_ + k) * C_ + c4 * 4;
  f16x4 hm; hm[0] = (f16)a0; hm[1] = (f16)a1; hm[2] = (f16)a2; hm[3] = (f16)a3;
  *(f16x4*)(muF + base) = hm;
  if (c4 == 0) zsA[b * K_ + k] = zs;
  if (LAST) {
    *(float4*)(outmu + base) = make_float4(a0, a1, a2, a3);
    muT[((size_t)b * C_ + c4 * 4 + 0) * K_ + k] = hm[0];
    muT[((size_t)b * C_ + c4 * 4 + 1) * K_ + k] = hm[1];
    muT[((size_t)b * C_ + c4 * 4 + 2) * K_ + k] = hm[2];
    muT[((size_t)b * C_ + c4 * 4 + 3) * K_ + k] = hm[3];
  }
}

// ---------------------------------------------------------------- k_attn
__global__ __launch_bounds__(256) void k_attn(
    const f16* __restrict__ zB, const float* __restrict__ cpB, float* __restrict__ attn)
{
  __shared__ float zt[64][68];
  __shared__ float inv_s[K_];
  int b = blockIdx.y, l0 = blockIdx.x * 64, t = threadIdx.x;
  if (t < K_) {
    float zs = 0.f;
#pragma unroll
    for (int chn = 0; chn < NCH; ++chn) zs += cpB[(size_t)chn * (B_ * K_) + b * K_ + t];
    inv_s[t] = 1.f / (EPSF + zs);
  }
  for (int p = 0; p < 16; ++p) {
    int e = t + p * 256, lo = e >> 6, k = e & 63;
    zt[lo][k] = (float)zB[((size_t)b * L_ + l0 + lo) * K_ + k];
  }
  __syncthreads();
  int lo = t & 63, kb = t >> 6;
  for (int p = 0; p < 16; ++p) {
    int k = kb * 16 + p;
    attn[((size_t)b * K_ + k) * L_ + l0 + lo] = zt[lo][k] * inv_s[k];
  }
}

// ---------------------------------------------------------------- k_mlp
// prologue: recon = (z*zinv) @ mu via MFMA into B-frag LDS layout.
// main loop: 2 barriers/iter; w1 LDS-dbuf staged; w2 A-frags from global (L2).
constexpr int W1S_OFF = 0;        // 2 x 32KB
constexpr int HS_OFF  = 65536;    // 17408 B
constexpr int BNS_OFF = 83200;    // 8192 B
constexpr int MUT_OFF = 0;        // prologue: 32KB
constexpr int ZS_OFF  = 32768;    // prologue: 16KB
constexpr int RCS_OFF = 49152;    // prologue: 64KB
constexpr int POOL_SZ = 114688;

__global__ __launch_bounds__(512, 2) void k_mlp(
    const f16* __restrict__ zA,                  // [BL][64]
    const f16* __restrict__ muT,                 // [B][C][K]
    const float* __restrict__ zsA,               // [B][K]
    const unsigned short* __restrict__ w1bf,     // [4096][256] bf16 (bn-scaled)
    const unsigned short* __restrict__ w2fr,     // [1048576] bf16 A-frag order
    const f16* __restrict__ bnshH, const float* __restrict__ b2,
    float* __restrict__ outr)                    // [BL][256] f32
{
  __shared__ __align__(16) char pool[POOL_SZ];
  __shared__ float zinv_s[K_];

  unsigned short* w1s = (unsigned short*)(pool + W1S_OFF);   // [2][64*256]
  unsigned short* hs  = (unsigned short*)(pool + HS_OFF);    // [128*68]
  f16* bns_s          = (f16*)(pool + BNS_OFF);              // [4096]
  f16* muT_s          = (f16*)(pool + MUT_OFF);
  f16* z_s            = (f16*)(pool + ZS_OFF);
  unsigned short* rcs = (unsigned short*)(pool + RCS_OFF);

  int t = threadIdx.x, w = t >> 6, lane = t & 63, l31 = lane & 31, l5 = lane >> 5;
  int rb = blockIdx.x * 128, b = rb >> 11, l0 = rb & 2047;
  int tt = w >> 1, ih = w & 1;   // GEMM1: tok-tile, i-half ; GEMM2: o-tile = w

  // ---- prologue staging
  if (t < K_) zinv_s[t] = 1.f / (EPSF + zsA[b * K_ + t]);
#pragma unroll
  for (int q = 0; q < 4; ++q) {
    int s = q * 512 + t, c = s >> 3, sl = s & 7;
    gload16(muT + ((size_t)b * C_ + c) * K_ + ((sl ^ (c & 7)) << 3), muT_s + s * 8);
  }
#pragma unroll
  for (int q = 0; q < 2; ++q) {
    int s = q * 512 + t, tok = s >> 3, sl = s & 7;
    gload16(zA + ((size_t)b * L_ + l0 + tok) * K_ + ((sl ^ (tok & 7)) << 3), z_s + s * 8);
  }
  asm volatile("s_waitcnt vmcnt(0) lgkmcnt(0)" ::: "memory");
  __builtin_amdgcn_s_barrier();
  __builtin_amdgcn_sched_barrier(0);

  // ---- recon MFMA: D[c 32][tok 32] per (tt, ih); K = 64
  {
    f16x8 bz[4];
#pragma unroll
    for (int kk = 0; kk < 4; ++kk) {
      int tok = tt * 32 + l31;
      f16x8 zr = *(const f16x8*)(z_s + tok * 64 + (((kk * 2 + l5) ^ (tok & 7)) << 3));
      f16x8 sc;
#pragma unroll
      for (int e = 0; e < 8; ++e)
        sc[e] = (f16)((float)zr[e] * zinv_s[kk * 16 + l5 * 8 + e]);
      bz[kk] = sc;
    }
    f32x16 d0, d1, d2, d3;
#pragma unroll
    for (int r = 0; r < 16; ++r) { d0[r] = 0.f; d1[r] = 0.f; d2[r] = 0.f; d3[r] = 0.f; }
#pragma unroll
    for (int kk = 0; kk < 4; ++kk) {
#pragma unroll
      for (int m = 0; m < 4; ++m) {
        int c = ih * 128 + m * 32 + l31;
        f16x8 am = *(const f16x8*)(muT_s + c * 64 + (((kk * 2 + l5) ^ (c & 7)) << 3));
        if (m == 0) d0 = __builtin_amdgcn_mfma_f32_32x32x16_f16(am, bz[kk], d0, 0, 0, 0);
        if (m == 1) d1 = __builtin_amdgcn_mfma_f32_32x32x16_f16(am, bz[kk], d1, 0, 0, 0);
        if (m == 2) d2 = __builtin_amdgcn_mfma_f32_32x32x16_f16(am, bz[kk], d2, 0, 0, 0);
        if (m == 3) d3 = __builtin_amdgcn_mfma_f32_32x32x16_f16(am, bz[kk], d3, 0, 0, 0);
      }
    }
    asm volatile("s_waitcnt lgkmcnt(0)" ::: "memory");
    __builtin_amdgcn_s_barrier();      // muT_s/z_s reads done -> rcs region usable
    __builtin_amdgcn_sched_barrier(0);
#pragma unroll
    for (int m = 0; m < 4; ++m) {
#pragma unroll
      for (int r = 0; r < 16; ++r) {
        int c = ih * 128 + m * 32 + (r & 3) + 8 * (r >> 2) + 4 * l5;
        int ks = c >> 4, l5p = (c >> 3) & 1, j = c & 7;
        float val = (m == 0) ? d0[r] : (m == 1) ? d1[r] : (m == 2) ? d2[r] : d3[r];
        rcs[(((tt * 16 + ks) * 64) + l5p * 32 + l31) * 8 + j] = f2bf(val);
      }
    }
  }
  asm volatile("s_waitcnt lgkmcnt(0)" ::: "memory");
  __builtin_amdgcn_s_barrier();
  __builtin_amdgcn_sched_barrier(0);

  // persistent recon B-frags for this wave's tok-tile
  bf16x8 rc[16];
#pragma unroll
  for (int ks = 0; ks < 16; ++ks)
    rc[ks] = *(const bf16x8*)(rcs + ((tt * 16 + ks) * 64 + lane) * 8);
  asm volatile("s_waitcnt lgkmcnt(0)" ::: "memory");
  __builtin_amdgcn_s_barrier();      // rc in regs -> pool reusable (w1s/bns)
  __builtin_amdgcn_sched_barrier(0);

  f32x16 acc2[4];
#pragma unroll
  for (int q = 0; q < 4; ++q)
#pragma unroll
    for (int r = 0; r < 16; ++r) acc2[q][r] = 0.f;

#define STAGE(ic, buf)                                                          \
  {                                                                             \
    _Pragma("unroll")                                                           \
    for (int q = 0; q < 4; ++q) {                                               \
      int d = q * 512 + t, i = d >> 5, sl = d & 31;                             \
      gload16(w1bf + (size_t)((ic) * 64 + i) * C_ + ((sl ^ (i & 15)) << 3),     \
              w1s + (size_t)(buf) * 16384 + d * 8);                             \
    }                                                                           \
  }

  // bns (8KB) + first w1 chunk
  gload16(bnshH + t * 8, bns_s + t * 8);
  STAGE(0, 0);
  asm volatile("s_waitcnt vmcnt(0)" ::: "memory");
  __builtin_amdgcn_s_barrier();
  __builtin_amdgcn_sched_barrier(0);

  const bf16x8* a2p = (const bf16x8*)w2fr;
  int a2base = l5 * 256 + w * 32 + l31;    // + (ic*4+ks2)*512

#pragma unroll 2
  for (int ic = 0; ic < 64; ++ic) {
    int cur = ic & 1;
    // entry invariant: w1s[cur] published; hs free
    // a2 prefetch (oldest vmem of this iter)
    bf16x8 a2r[4];
#pragma unroll
    for (int ks2 = 0; ks2 < 4; ++ks2)
      a2r[ks2] = a2p[(size_t)(ic * 4 + ks2) * 512 + a2base];
    __builtin_amdgcn_sched_barrier(0);
    if (ic < 63) STAGE(ic + 1, cur ^ 1);
    __builtin_amdgcn_sched_barrier(0);

    // ---- GEMM1: h[i 32][tok 32] for (ih, tt)
    f32x16 h0, h1;
#pragma unroll
    for (int r = 0; r < 16; ++r) { h0[r] = 0.f; h1[r] = 0.f; }
    int irow = ih * 32 + l31;
#pragma unroll
    for (int ks = 0; ks < 16; ++ks) {
      bf16x8 a1 = *(const bf16x8*)(w1s + cur * 16384 + irow * 256 +
                                   (((ks * 2 + l5) ^ (irow & 15)) << 3));
      if (ks & 1) h1 = __builtin_amdgcn_mfma_f32_32x32x16_bf16(a1, rc[ks], h1, 0, 0, 0);
      else        h0 = __builtin_amdgcn_mfma_f32_32x32x16_bf16(a1, rc[ks], h0, 0, 0, 0);
    }
#pragma unroll
    for (int r = 0; r < 16; ++r) h0[r] += h1[r];

    // ---- BN shift + ReLU -> hs (vectorized bns reads, packed b32 stores)
    {
      f16x4 bnv[4];
#pragma unroll
      for (int q = 0; q < 4; ++q)
        bnv[q] = *(const f16x4*)(bns_s + ic * 64 + ih * 32 + q * 8 + l5 * 4);
#pragma unroll
      for (int q = 0; q < 4; ++q) {
#pragma unroll
        for (int pr = 0; pr < 2; ++pr) {
          int r0 = q * 4 + pr * 2;                  // h regs r0, r0+1 -> il, il+1
          int il = ih * 32 + q * 8 + 4 * l5 + pr * 2;
          float v0 = fmaxf(h0[r0]     + (float)bnv[q][pr * 2],     0.f);
          float v1 = fmaxf(h0[r0 + 1] + (float)bnv[q][pr * 2 + 1], 0.f);
          unsigned u = (unsigned)f2bf(v0) | ((unsigned)f2bf(v1) << 16);
          *(unsigned*)(hs + (tt * 32 + l31) * 68 + il) = u;
        }
      }
    }
    asm volatile("s_waitcnt lgkmcnt(0)" ::: "memory");
    __builtin_amdgcn_s_barrier();      // hs published
    __builtin_amdgcn_sched_barrier(0);

    // ---- GEMM2: wave w owns o-tile, all 4 tok-tiles, k=64
    __builtin_amdgcn_s_setprio(1);
#pragma unroll
    for (int ks2 = 0; ks2 < 4; ++ks2) {
#pragma unroll
      for (int t2 = 0; t2 < 4; ++t2) {
        bf16x8 bh = *(const bf16x8*)(hs + (t2 * 32 + l31) * 68 + ks2 * 16 + l5 * 8);
        acc2[t2] = __builtin_amdgcn_mfma_f32_32x32x16_bf16(a2r[ks2], bh, acc2[t2], 0, 0, 0);
      }
    }
    __builtin_amdgcn_s_setprio(0);
    // end barrier: STAGE(ic+1) landed for everyone; hs reads done
    asm volatile("s_waitcnt vmcnt(0) lgkmcnt(0)" ::: "memory");
    __builtin_amdgcn_s_barrier();
    __builtin_amdgcn_sched_barrier(0);
  }
#undef STAGE

  // ---- epilogue: + b2, f32x4 stores
#pragma unroll
  for (int t2 = 0; t2 < 4; ++t2) {
    int tok = rb + t2 * 32 + l31;
#pragma unroll
    for (int q = 0; q < 4; ++q) {
      int o = w * 32 + q * 8 + l5 * 4;
      float4 bias = *(const float4*)(b2 + o);
      f32x4 v;
      v[0] = acc2[t2][q * 4 + 0] + bias.x;
      v[1] = acc2[t2][q * 4 + 1] + bias.y;
      v[2] = acc2[t2][q * 4 + 2] + bias.z;
      v[3] = acc2[t2][q * 4 + 3] + bias.w;
      *(f32x4*)(outr + (size_t)tok * C_ + o) = v;
    }
  }
}

// ---------------------------------------------------------------- launch
extern "C" void kernel_launch(void* const* d_in, const int* in_sizes, int n_in,
                              void* d_out, int out_size, void* d_ws, size_t ws_size,
                              hipStream_t stream)
{
  const float* x     = (const float*)d_in[0];
  const float* mu0   = (const float*)d_in[2];
  const float* w1    = (const float*)d_in[3];
  const float* b1    = (const float*)d_in[4];
  const float* gamma = (const float*)d_in[5];
  const float* beta  = (const float*)d_in[6];
  const float* bmean = (const float*)d_in[7];
  const float* bvar  = (const float*)d_in[8];
  const float* w2    = (const float*)d_in[9];
  const float* b2    = (const float*)d_in[10];
  float* out = (float*)d_out;

  char* wsb = (char*)d_ws;
  f16* part = (f16*)(wsb + 0);                                  // 8,388,608 B
  f16* zB   = part;                                             // alias (dead after last mufin)
  f16* zA   = (f16*)(wsb + 8388608);                            // 4,194,304
  f16* xf   = (f16*)(wsb + 12582912);                           // 16,777,216
  f16* xTf  = (f16*)(wsb + 29360128);                           // 16,777,216
  unsigned short* w1bf = (unsigned short*)(wsb + 46137344);     // 2,097,152
  unsigned short* w2fr = (unsigned short*)(wsb + 48234496);     // 2,097,152
  f16*   muF   = (f16*)(wsb + 50331648);                        // 524,288
  f16*   muT   = (f16*)(wsb + 50855936);                        // 524,288
  f16*   bnshH = (f16*)(wsb + 51380224);                        // 8,192
  float* cpA   = (float*)(wsb + 51388416);                      // 65,536
  float* cpB   = (float*)(wsb + 51453952);                      // 65,536
  float* zsA   = (float*)(wsb + 51519488);                      // 4,096  (~51.5MB)

  k_pre<<<4096, 256, 0, stream>>>(w1, w2, gamma, beta, bmean, bvar, b1, mu0,
                                  w1bf, w2fr, bnshH, muF);
  k_xT<<<dim3(32, 4, 16), 256, 0, stream>>>(x, xf, xTf);

  for (int s = 0; s < 10; ++s) {
    if (s == 9) k_em<true, true ><<<dim3(16, 16), 512, 0, stream>>>(xf, xTf, muF, zA, cpA, part);
    else        k_em<true, false><<<dim3(16, 16), 512, 0, stream>>>(xf, xTf, muF, zA, cpA, part);
    if (s == 9) k_mufin<true ><<<256, 256, 0, stream>>>(part, cpA, muF, muT, zsA, out);
    else        k_mufin<false><<<256, 256, 0, stream>>>(part, cpA, muF, muT, zsA, out);
  }
  // new_z with final mu (no mu-update; zB overlays dead part buffer)
  k_em<false, true><<<dim3(16, 16), 512, 0, stream>>>(xf, xTf, muF, zB, cpB, part);
  k_attn<<<dim3(32, 16), 256, 0, stream>>>(zB, cpB, out + 262144);
  k_mlp<<<256, 512, 0, stream>>>(zA, muT, zsA, w1bf, w2fr, bnshH, b2, out + 2359296);
}

// Round 7
// 424.698 us; speedup vs baseline: 1.2320x; 1.2320x over previous
//
#include <hip/hip_runtime.h>

constexpr int B_ = 16, L_ = 2048, C_ = 256, K_ = 64, INNER_ = 4096;
constexpr int NCH = 32;          // L-chunks (RPB=64)
constexpr int RPB = 64;          // rows per k_em block
#define EPSF 1e-6f

typedef __attribute__((ext_vector_type(8)))  short bf16x8;
typedef __attribute__((ext_vector_type(4)))  float f32x4;
typedef __attribute__((ext_vector_type(16))) float f32x16;
typedef _Float16 f16;
typedef __attribute__((ext_vector_type(8))) _Float16 f16x8;
typedef __attribute__((ext_vector_type(4))) _Float16 f16x4;

__device__ __forceinline__ unsigned short f2bf(float f) {
  union { float f; unsigned u; } v; v.f = f;
  unsigned r = v.u + 0x7fffu + ((v.u >> 16) & 1u);   // RNE
  return (unsigned short)(r >> 16);
}

__device__ __forceinline__ void gload16(const void* src, void* lds) {
  __builtin_amdgcn_global_load_lds(
      (const __attribute__((address_space(1))) unsigned*)src,
      (__attribute__((address_space(3))) unsigned*)lds, 16, 0, 0);
}

// ---------------------------------------------------------------- k_pre
__global__ __launch_bounds__(256) void k_pre(
    const float* __restrict__ w1, const float* __restrict__ w2,
    const float* __restrict__ gamma, const float* __restrict__ beta,
    const float* __restrict__ bmean, const float* __restrict__ bvar,
    const float* __restrict__ b1, const float* __restrict__ mu0,
    unsigned short* __restrict__ w1bf, unsigned short* __restrict__ w2fr,
    f16* __restrict__ bnshH, f16* __restrict__ muF)
{
  int i = blockIdx.x * 256 + threadIdx.x;     // covers 1048576
  if (i < INNER_ * C_) {
    int r = i >> 8;
    float sc = gamma[r] * rsqrtf(bvar[r] + 1e-5f);
    w1bf[i] = f2bf(w1[i] * sc);
    // w2fr A-frag order: elem f = i>>3 = ((ks*2+l5)*8 + ow)*32 + l31, j = i&7
    int j = i & 7, l31 = (i >> 3) & 31, ow = (i >> 8) & 7, l5 = (i >> 11) & 1, ks = i >> 12;
    int ii = ks * 16 + l5 * 8 + j;
    int o  = ow * 32 + l31;
    w2fr[i] = f2bf(w2[(size_t)o * INNER_ + ii]);
  }
  if (i < B_ * K_ * C_) muF[i] = (f16)mu0[i & (K_ * C_ - 1)];
  if (i < INNER_) {
    float sc = gamma[i] * rsqrtf(bvar[i] + 1e-5f);
    bnshH[i] = (f16)fmaf(b1[i] - bmean[i], sc, beta[i]);
  }
}

// ---------------------------------------------------------------- k_xT
__global__ __launch_bounds__(256) void k_xT(const float* __restrict__ x,
                                            f16* __restrict__ xf, f16* __restrict__ xTf)
{
  __shared__ float ts[64][65];
  int l0 = blockIdx.x * 64, c0 = blockIdx.y * 64, b = blockIdx.z;
  int t = threadIdx.x;
  for (int p = 0; p < 16; ++p) {
    int e = t + p * 256, i = e >> 6, j = e & 63;
    float vv = x[((size_t)b * L_ + l0 + i) * C_ + c0 + j];
    ts[i][j] = vv;
    xf[((size_t)b * L_ + l0 + i) * C_ + c0 + j] = (f16)vv;
  }
  __syncthreads();
  for (int p = 0; p < 16; ++p) {
    int e = t + p * 256, i = e >> 6, j = e & 63;
    xTf[((size_t)b * C_ + c0 + i) * L_ + l0 + j] = (f16)ts[j][i];
  }
}

// ---------------------------------------------------------------- k_em
// 256 thr / 4 waves, RPB=64, 2 blocks/CU. Same schedule as r5 (validated),
// smaller tile: S^T=mu.x^T -> in-reg softmax -> z -> colsum -> part=z^T.xT.
template<bool DO_MU, bool WRITE_Z>
__global__ __launch_bounds__(256, 2) void k_em(
    const f16* __restrict__ xf,    // [B][L][C]
    const f16* __restrict__ xTf,   // [B][C][L]
    const f16* __restrict__ muF,   // [B][K][C]
    f16* __restrict__ zout,        // [B][L][K]
    float* __restrict__ cp,        // [NCH][B*K]
    f16* __restrict__ part)        // [NCH][B][K][C]
{
  __shared__ f16 mu_s[K_ * C_];     // 32KB, slot ^ (k&15)
  __shared__ f16 zT_s[K_ * RPB];    // 8KB,  slot ^ (k&7)
  __shared__ f16 xtile[C_ * RPB];   // 32KB, slot ^ (c&7)
  __shared__ float cpart[4][K_];

  int t = threadIdx.x, b = blockIdx.y, chn = blockIdx.x, l0 = chn * RPB;
  int w = t >> 6, lane = t & 63, l15 = lane & 15, g = lane >> 4;

  // stage mu (2048 slots, 8/thread) -- OLDEST vmem
#pragma unroll
  for (int q = 0; q < 8; ++q) {
    int s = q * 256 + t, k = s >> 5, sl = s & 31;
    gload16(muF + (size_t)b * (K_ * C_) + k * C_ + ((sl ^ (k & 15)) << 3), mu_s + s * 8);
  }
  __builtin_amdgcn_sched_barrier(0);
  f16x8 xfr[8];
  const f16* xr = xf + ((size_t)b * L_ + l0 + w * 16 + l15) * C_ + g * 8;
#pragma unroll
  for (int ck = 0; ck < 8; ++ck) xfr[ck] = *(const f16x8*)(xr + ck * 32);
  __builtin_amdgcn_sched_barrier(0);
  if (DO_MU) {
    // stage xT tile (2048 slots, 8/thread) -- NEWEST, stays in flight
#pragma unroll
    for (int q = 0; q < 8; ++q) {
      int s = q * 256 + t, c = s >> 3, sl = s & 7;
      gload16(xTf + (size_t)(b * C_ + c) * L_ + l0 + ((sl ^ (c & 7)) << 3), xtile + s * 8);
    }
    __builtin_amdgcn_sched_barrier(0);
    asm volatile("s_waitcnt vmcnt(8)" ::: "memory");   // mu+xfr landed; xtile in flight
  } else {
    asm volatile("s_waitcnt vmcnt(0)" ::: "memory");
  }
  __builtin_amdgcn_s_barrier();
  __builtin_amdgcn_sched_barrier(0);

  // ---- phase1: S^T[k][tok], wave w owns tok tile w (16 toks)
  f32x4 acc[4];
#pragma unroll
  for (int mt = 0; mt < 4; ++mt)
#pragma unroll
    for (int j = 0; j < 4; ++j) acc[mt][j] = 0.f;
#pragma unroll
  for (int ck = 0; ck < 8; ++ck) {
#pragma unroll
    for (int mt = 0; mt < 4; ++mt) {
      f16x8 a = *(const f16x8*)(mu_s + (mt * 16 + l15) * C_ + (((ck * 4 + g) ^ l15) << 3));
      acc[mt] = __builtin_amdgcn_mfma_f32_16x16x32_f16(a, xfr[ck], acc[mt], 0, 0, 0);
    }
  }

  // ---- phase2: softmax over k; lane holds k = mt*16+g*4+jj for tok = w*16+l15
  float z[4][4];
  {
    float mx = acc[0][0];
#pragma unroll
    for (int mt = 0; mt < 4; ++mt)
#pragma unroll
      for (int jj = 0; jj < 4; ++jj) mx = fmaxf(mx, acc[mt][jj]);
    mx = fmaxf(mx, __shfl_xor(mx, 16, 64));
    mx = fmaxf(mx, __shfl_xor(mx, 32, 64));
    float sm = 0.f;
#pragma unroll
    for (int mt = 0; mt < 4; ++mt)
#pragma unroll
      for (int jj = 0; jj < 4; ++jj) {
        float e = __expf(acc[mt][jj] - mx);
        z[mt][jj] = e; sm += e;
      }
    sm += __shfl_xor(sm, 16, 64);
    sm += __shfl_xor(sm, 32, 64);
    float inv = 1.f / sm;
#pragma unroll
    for (int mt = 0; mt < 4; ++mt)
#pragma unroll
      for (int jj = 0; jj < 4; ++jj) z[mt][jj] *= inv;
  }

  // colsum partial
#pragma unroll
  for (int mt = 0; mt < 4; ++mt)
#pragma unroll
    for (int jj = 0; jj < 4; ++jj) {
      float v = z[mt][jj];
      v += __shfl_xor(v, 1, 64); v += __shfl_xor(v, 2, 64);
      v += __shfl_xor(v, 4, 64); v += __shfl_xor(v, 8, 64);
      if (l15 == 0) cpart[w][mt * 16 + g * 4 + jj] = v;
    }

  // z -> zT LDS (slot ^ (k&7)) and/or z global
#pragma unroll
  for (int mt = 0; mt < 4; ++mt)
#pragma unroll
    for (int jj = 0; jj < 4; ++jj) {
      int k = mt * 16 + g * 4 + jj;
      int tl = w * 16 + l15;
      f16 h = (f16)z[mt][jj];
      if (DO_MU)   zT_s[k * RPB + (((tl >> 3) ^ (k & 7)) << 3) + (tl & 7)] = h;
      if (WRITE_Z) zout[((size_t)b * L_ + l0 + tl) * K_ + k] = h;
    }
  __syncthreads();   // zT/cpart ready; full drain -> xtile landed

  if (t < K_) {
    float s = 0.f;
#pragma unroll
    for (int q = 0; q < 4; ++q) s += cpart[q][t];
    cp[(size_t)chn * (B_ * K_) + b * K_ + t] = s;
  }

  // ---- phase3: part[k][c] = z^T . xT, wave w owns c-quarter w*64
  if (DO_MU) {
    f32x4 a3[4][4];
#pragma unroll
    for (int mt = 0; mt < 4; ++mt)
#pragma unroll
      for (int nt = 0; nt < 4; ++nt)
#pragma unroll
        for (int j = 0; j < 4; ++j) a3[mt][nt][j] = 0.f;
    int cb = w * 64;
#pragma unroll
    for (int ks = 0; ks < 2; ++ks) {
      f16x8 az[4], bx[4];
#pragma unroll
      for (int mt = 0; mt < 4; ++mt)
        az[mt] = *(const f16x8*)(zT_s + (mt * 16 + l15) * RPB + (((ks * 4 + g) ^ (l15 & 7)) << 3));
#pragma unroll
      for (int nt = 0; nt < 4; ++nt) {
        int c = cb + nt * 16 + l15;
        bx[nt] = *(const f16x8*)(xtile + c * RPB + (((ks * 4 + g) ^ (c & 7)) << 3));
      }
#pragma unroll
      for (int mt = 0; mt < 4; ++mt)
#pragma unroll
        for (int nt = 0; nt < 4; ++nt)
          a3[mt][nt] = __builtin_amdgcn_mfma_f32_16x16x32_f16(az[mt], bx[nt], a3[mt][nt], 0, 0, 0);
    }
    f16* pp = part + (((size_t)chn * B_ + b) * K_) * C_;
#pragma unroll
    for (int mt = 0; mt < 4; ++mt)
#pragma unroll
      for (int nt = 0; nt < 4; ++nt)
#pragma unroll
        for (int jj = 0; jj < 4; ++jj)
          pp[(size_t)(mt * 16 + g * 4 + jj) * C_ + cb + nt * 16 + l15] = (f16)a3[mt][nt][jj];
  }
}

// ---------------------------------------------------------------- k_mufin
template<bool LAST>
__global__ __launch_bounds__(256) void k_mufin(
    const f16* __restrict__ part, const float* __restrict__ cp,
    f16* __restrict__ muF, f16* __restrict__ muT,
    float* __restrict__ zsA, float* __restrict__ outmu)
{
  int b = blockIdx.x >> 4, kg = blockIdx.x & 15, t = threadIdx.x;
  int kr = t >> 6, c4 = t & 63, k = kg * 4 + kr;
  float a0 = 0.f, a1 = 0.f, a2 = 0.f, a3 = 0.f;
#pragma unroll
  for (int chn = 0; chn < NCH; ++chn) {
    f16x4 p = *(const f16x4*)(part + (((size_t)chn * B_ + b) * K_ + k) * C_ + c4 * 4);
    a0 += (float)p[0]; a1 += (float)p[1]; a2 += (float)p[2]; a3 += (float)p[3];
  }
  float zs = 0.f;
#pragma unroll
  for (int chn = 0; chn < NCH; ++chn) zs += cp[(size_t)chn * (B_ * K_) + b * K_ + k];
  float sc = 1.f / (EPSF + zs);
  a0 *= sc; a1 *= sc; a2 *= sc; a3 *= sc;
  float ssq = a0 * a0 + a1 * a1 + a2 * a2 + a3 * a3;
#pragma unroll
  for (int off = 32; off >= 1; off >>= 1) ssq += __shfl_xor(ssq, off, 64);
  float inv = 1.f / (EPSF + sqrtf(ssq));
  a0 *= inv; a1 *= inv; a2 *= inv; a3 *= inv;
  size_t base = (size_t)(b * K_ + k) * C_ + c4 * 4;
  f16x4 hm; hm[0] = (f16)a0; hm[1] = (f16)a1; hm[2] = (f16)a2; hm[3] = (f16)a3;
  *(f16x4*)(muF + base) = hm;
  if (c4 == 0) zsA[b * K_ + k] = zs;
  if (LAST) {
    *(float4*)(outmu + base) = make_float4(a0, a1, a2, a3);
    muT[((size_t)b * C_ + c4 * 4 + 0) * K_ + k] = hm[0];
    muT[((size_t)b * C_ + c4 * 4 + 1) * K_ + k] = hm[1];
    muT[((size_t)b * C_ + c4 * 4 + 2) * K_ + k] = hm[2];
    muT[((size_t)b * C_ + c4 * 4 + 3) * K_ + k] = hm[3];
  }
}

// ---------------------------------------------------------------- k_attn
__global__ __launch_bounds__(256) void k_attn(
    const f16* __restrict__ zB, const float* __restrict__ cpB, float* __restrict__ attn)
{
  __shared__ float zt[64][68];
  __shared__ float inv_s[K_];
  int b = blockIdx.y, l0 = blockIdx.x * 64, t = threadIdx.x;
  if (t < K_) {
    float zs = 0.f;
#pragma unroll
    for (int chn = 0; chn < NCH; ++chn) zs += cpB[(size_t)chn * (B_ * K_) + b * K_ + t];
    inv_s[t] = 1.f / (EPSF + zs);
  }
  for (int p = 0; p < 16; ++p) {
    int e = t + p * 256, lo = e >> 6, k = e & 63;
    zt[lo][k] = (float)zB[((size_t)b * L_ + l0 + lo) * K_ + k];
  }
  __syncthreads();
  int lo = t & 63, kb = t >> 6;
  for (int p = 0; p < 16; ++p) {
    int k = kb * 16 + p;
    attn[((size_t)b * K_ + k) * L_ + l0 + lo] = zt[lo][k] * inv_s[k];
  }
}

// ---------------------------------------------------------------- k_mlp
// 256 thr / 4 waves, 64 toks/block, grid 512 = 2 blocks/CU.
// All per-iter vmem waits are for iter-old loads (counted vmcnt).
constexpr int W1S_OFF  = 0;        // 2 x 32KB dbuf
constexpr int HS_OFF   = 65536;    // 64*68*2 = 8704
constexpr int ZINV_OFF = 74240;    // 256
constexpr int MUT_OFF  = 0;        // prologue: 32KB
constexpr int ZS_OFF   = 32768;    // prologue: 8KB
constexpr int RCS_OFF  = 40960;    // prologue: 32KB (ends 73728)
constexpr int POOL_SZ  = 74496;

__global__ __launch_bounds__(256, 2) void k_mlp(
    const f16* __restrict__ zA,                  // [BL][64]
    const f16* __restrict__ muT,                 // [B][C][K]
    const float* __restrict__ zsA,               // [B][K]
    const unsigned short* __restrict__ w1bf,     // [4096][256] bf16 (bn-scaled)
    const unsigned short* __restrict__ w2fr,     // [1048576] bf16 A-frag order
    const f16* __restrict__ bnshH, const float* __restrict__ b2,
    float* __restrict__ outr)                    // [BL][256] f32
{
  __shared__ __align__(16) char pool[POOL_SZ];
  unsigned short* w1s = (unsigned short*)(pool + W1S_OFF);
  unsigned short* hs  = (unsigned short*)(pool + HS_OFF);
  float* zinv_s       = (float*)(pool + ZINV_OFF);
  f16* muT_s          = (f16*)(pool + MUT_OFF);
  f16* z_s            = (f16*)(pool + ZS_OFF);
  unsigned short* rcs = (unsigned short*)(pool + RCS_OFF);

  int t = threadIdx.x, w = t >> 6, lane = t & 63, l31 = lane & 31, l5 = lane >> 5;
  int rb = blockIdx.x * 64, b = rb >> 11, l0 = rb & 2047;
  int th = w >> 1, ih = w & 1;   // GEMM1: tok-tile(2), i-half(2)

  // ---- prologue staging: zinv + muT (8/thr) + z (2/thr)
  if (t < K_) zinv_s[t] = 1.f / (EPSF + zsA[b * K_ + t]);
#pragma unroll
  for (int q = 0; q < 8; ++q) {
    int s = q * 256 + t, c = s >> 3, sl = s & 7;
    gload16(muT + ((size_t)b * C_ + c) * K_ + ((sl ^ (c & 7)) << 3), muT_s + s * 8);
  }
#pragma unroll
  for (int q = 0; q < 2; ++q) {
    int s = q * 256 + t, tok = s >> 3, sl = s & 7;
    gload16(zA + ((size_t)b * L_ + l0 + tok) * K_ + ((sl ^ (tok & 7)) << 3), z_s + s * 8);
  }
  asm volatile("s_waitcnt vmcnt(0) lgkmcnt(0)" ::: "memory");
  __builtin_amdgcn_s_barrier();
  __builtin_amdgcn_sched_barrier(0);

  // ---- recon MFMA: wave w owns c-range w*64 (m 2), both tok-tiles (tt 2), K=64
  {
    f32x16 d[2][2];
#pragma unroll
    for (int m = 0; m < 2; ++m)
#pragma unroll
      for (int tt = 0; tt < 2; ++tt)
#pragma unroll
        for (int r = 0; r < 16; ++r) d[m][tt][r] = 0.f;
#pragma unroll
    for (int kk = 0; kk < 4; ++kk) {
      f16x8 bz[2];
#pragma unroll
      for (int tt = 0; tt < 2; ++tt) {
        int tok = tt * 32 + l31;
        f16x8 zr = *(const f16x8*)(z_s + tok * 64 + (((kk * 2 + l5) ^ (tok & 7)) << 3));
        f16x8 sc2;
#pragma unroll
        for (int e = 0; e < 8; ++e)
          sc2[e] = (f16)((float)zr[e] * zinv_s[kk * 16 + l5 * 8 + e]);
        bz[tt] = sc2;
      }
#pragma unroll
      for (int m = 0; m < 2; ++m) {
        int c = w * 64 + m * 32 + l31;
        f16x8 am = *(const f16x8*)(muT_s + c * 64 + (((kk * 2 + l5) ^ (c & 7)) << 3));
#pragma unroll
        for (int tt = 0; tt < 2; ++tt)
          d[m][tt] = __builtin_amdgcn_mfma_f32_32x32x16_f16(am, bz[tt], d[m][tt], 0, 0, 0);
      }
    }
    // scatter into B-frag layout (rcs region disjoint from muT_s/z_s)
#pragma unroll
    for (int m = 0; m < 2; ++m)
#pragma unroll
      for (int tt = 0; tt < 2; ++tt)
#pragma unroll
        for (int r = 0; r < 16; ++r) {
          int c = w * 64 + m * 32 + (r & 3) + 8 * (r >> 2) + 4 * l5;
          int ks = c >> 4, l5p = (c >> 3) & 1, j = c & 7;
          rcs[(((tt * 16 + ks) * 64) + l5p * 32 + l31) * 8 + j] = f2bf(d[m][tt][r]);
        }
  }
  asm volatile("s_waitcnt lgkmcnt(0)" ::: "memory");
  __builtin_amdgcn_s_barrier();        // rcs complete (cross-wave)
  __builtin_amdgcn_sched_barrier(0);

  // persistent recon B-frags for this wave's tok-tile th
  bf16x8 rc[16];
#pragma unroll
  for (int ks = 0; ks < 16; ++ks)
    rc[ks] = *(const bf16x8*)(rcs + ((th * 16 + ks) * 64 + lane) * 8);
  asm volatile("s_waitcnt lgkmcnt(0)" ::: "memory");
  __builtin_amdgcn_s_barrier();        // rc in regs -> pool reusable
  __builtin_amdgcn_sched_barrier(0);

  f32x16 acc2[2][2];                   // [o-tile oi][tok-tile t2]
#pragma unroll
  for (int oi = 0; oi < 2; ++oi)
#pragma unroll
    for (int t2 = 0; t2 < 2; ++t2)
#pragma unroll
      for (int r = 0; r < 16; ++r) acc2[oi][t2][r] = 0.f;

#define STAGE(ic, buf)                                                          \
  {                                                                             \
    _Pragma("unroll")                                                           \
    for (int q = 0; q < 4; ++q) {                                               \
      int d2 = q * 256 + t, i = d2 >> 5, sl = d2 & 31;                          \
      gload16(w1bf + (size_t)((ic) * 64 + i) * C_ + ((sl ^ (i & 15)) << 3),     \
              w1s + (size_t)(buf) * 16384 + d2 * 8);                            \
    }                                                                           \
  }

  STAGE(0, 0);                         // outstanding = 4 (invariant)
  const bf16x8* a2p = (const bf16x8*)w2fr;

  for (int ic = 0; ic < 64; ++ic) {
    int cur = ic & 1;
    int icn = (ic < 63) ? ic + 1 : 63;
    // vmem issue order (pinned): bnv(ic) -> a2r(ic) -> STAGE(ic+1)
    f16x4 bnv[4];
#pragma unroll
    for (int q = 0; q < 4; ++q)
      bnv[q] = *(const f16x4*)(bnshH + ic * 64 + ih * 32 + q * 8 + 4 * l5);
    __builtin_amdgcn_sched_barrier(0);
    bf16x8 a2r[2][4];
#pragma unroll
    for (int oi = 0; oi < 2; ++oi)
#pragma unroll
      for (int ks2 = 0; ks2 < 4; ++ks2)
        a2r[oi][ks2] = a2p[(size_t)((ic * 4 + ks2) * 2 + l5) * 256 + (w * 2 + oi) * 32 + l31];
    __builtin_amdgcn_sched_barrier(0);
    STAGE(icn, cur ^ 1);
    __builtin_amdgcn_sched_barrier(0);
    // drain iter-old: STAGE(ic) + bnv(ic); leave a2r(ic)(8) + STAGE(ic+1)(4)
    asm volatile("s_waitcnt vmcnt(12)" ::: "memory");
    __builtin_amdgcn_s_barrier();
    __builtin_amdgcn_sched_barrier(0);

    // ---- GEMM1: h[i 32][tok 32] for (ih, th)
    f32x16 h0, h1;
#pragma unroll
    for (int r = 0; r < 16; ++r) { h0[r] = 0.f; h1[r] = 0.f; }
    int irow = ih * 32 + l31;
#pragma unroll
    for (int ks = 0; ks < 16; ++ks) {
      bf16x8 a1 = *(const bf16x8*)(w1s + cur * 16384 + irow * 256 +
                                   (((ks * 2 + l5) ^ (irow & 15)) << 3));
      if (ks & 1) h1 = __builtin_amdgcn_mfma_f32_32x32x16_bf16(a1, rc[ks], h1, 0, 0, 0);
      else        h0 = __builtin_amdgcn_mfma_f32_32x32x16_bf16(a1, rc[ks], h0, 0, 0, 0);
    }
#pragma unroll
    for (int r = 0; r < 16; ++r) h0[r] += h1[r];

    // ---- BN shift + ReLU -> hs (packed b32 stores), stride 68
#pragma unroll
    for (int q = 0; q < 4; ++q) {
#pragma unroll
      for (int pr = 0; pr < 2; ++pr) {
        int r0 = q * 4 + pr * 2;
        int il = ih * 32 + q * 8 + 4 * l5 + pr * 2;
        float v0 = fmaxf(h0[r0]     + (float)bnv[q][pr * 2],     0.f);
        float v1 = fmaxf(h0[r0 + 1] + (float)bnv[q][pr * 2 + 1], 0.f);
        unsigned u = (unsigned)f2bf(v0) | ((unsigned)f2bf(v1) << 16);
        *(unsigned*)(hs + (th * 32 + l31) * 68 + il) = u;
      }
    }
    asm volatile("s_waitcnt lgkmcnt(0)" ::: "memory");
    __builtin_amdgcn_s_barrier();       // hs published
    __builtin_amdgcn_sched_barrier(0);
    // a2r(ic) landed (leave STAGE(ic+1) in flight)
    asm volatile("s_waitcnt vmcnt(4)" ::: "memory");

    // ---- GEMM2: wave owns o-range w*64 (2 tiles), both tok-tiles, k=64
    __builtin_amdgcn_s_setprio(1);
#pragma unroll
    for (int ks2 = 0; ks2 < 4; ++ks2) {
      bf16x8 bh[2];
#pragma unroll
      for (int t2 = 0; t2 < 2; ++t2)
        bh[t2] = *(const bf16x8*)(hs + (t2 * 32 + l31) * 68 + ks2 * 16 + l5 * 8);
#pragma unroll
      for (int oi = 0; oi < 2; ++oi)
#pragma unroll
        for (int t2 = 0; t2 < 2; ++t2)
          acc2[oi][t2] = __builtin_amdgcn_mfma_f32_32x32x16_bf16(a2r[oi][ks2], bh[t2], acc2[oi][t2], 0, 0, 0);
    }
    __builtin_amdgcn_s_setprio(0);
    asm volatile("s_waitcnt lgkmcnt(0)" ::: "memory");   // hs reads done; NO vmcnt drain
    __builtin_amdgcn_s_barrier();
    __builtin_amdgcn_sched_barrier(0);
  }
#undef STAGE

  // ---- epilogue: + b2, f32x4 stores
#pragma unroll
  for (int oi = 0; oi < 2; ++oi) {
#pragma unroll
    for (int t2 = 0; t2 < 2; ++t2) {
      int tok = rb + t2 * 32 + l31;
#pragma unroll
      for (int q = 0; q < 4; ++q) {
        int o = (w * 2 + oi) * 32 + q * 8 + l5 * 4;
        float4 bias = *(const float4*)(b2 + o);
        f32x4 v;
        v[0] = acc2[oi][t2][q * 4 + 0] + bias.x;
        v[1] = acc2[oi][t2][q * 4 + 1] + bias.y;
        v[2] = acc2[oi][t2][q * 4 + 2] + bias.z;
        v[3] = acc2[oi][t2][q * 4 + 3] + bias.w;
        *(f32x4*)(outr + (size_t)tok * C_ + o) = v;
      }
    }
  }
}

// ---------------------------------------------------------------- launch
extern "C" void kernel_launch(void* const* d_in, const int* in_sizes, int n_in,
                              void* d_out, int out_size, void* d_ws, size_t ws_size,
                              hipStream_t stream)
{
  const float* x     = (const float*)d_in[0];
  const float* mu0   = (const float*)d_in[2];
  const float* w1    = (const float*)d_in[3];
  const float* b1    = (const float*)d_in[4];
  const float* gamma = (const float*)d_in[5];
  const float* beta  = (const float*)d_in[6];
  const float* bmean = (const float*)d_in[7];
  const float* bvar  = (const float*)d_in[8];
  const float* w2    = (const float*)d_in[9];
  const float* b2    = (const float*)d_in[10];
  float* out = (float*)d_out;

  char* wsb = (char*)d_ws;
  f16* part = (f16*)(wsb + 0);                                  // 16,777,216 B
  f16* zB   = part;                                             // alias (dead after last mufin)
  f16* zA   = (f16*)(wsb + 16777216);                           // 4,194,304
  f16* xf   = (f16*)(wsb + 20971520);                           // 16,777,216
  f16* xTf  = (f16*)(wsb + 37748736);                           // 16,777,216
  unsigned short* w1bf = (unsigned short*)(wsb + 54525952);     // 2,097,152
  unsigned short* w2fr = (unsigned short*)(wsb + 56623104);     // 2,097,152
  f16*   muF   = (f16*)(wsb + 58720256);                        // 524,288
  f16*   muT   = (f16*)(wsb + 59244544);                        // 524,288
  f16*   bnshH = (f16*)(wsb + 59768832);                        // 8,192
  float* cpA   = (float*)(wsb + 59777024);                      // 131,072
  float* cpB   = (float*)(wsb + 59908096);                      // 131,072
  float* zsA   = (float*)(wsb + 60039168);                      // 4,096  (~60MB)

  k_pre<<<4096, 256, 0, stream>>>(w1, w2, gamma, beta, bmean, bvar, b1, mu0,
                                  w1bf, w2fr, bnshH, muF);
  k_xT<<<dim3(32, 4, 16), 256, 0, stream>>>(x, xf, xTf);

  for (int s = 0; s < 10; ++s) {
    if (s == 9) k_em<true, true ><<<dim3(NCH, 16), 256, 0, stream>>>(xf, xTf, muF, zA, cpA, part);
    else        k_em<true, false><<<dim3(NCH, 16), 256, 0, stream>>>(xf, xTf, muF, zA, cpA, part);
    if (s == 9) k_mufin<true ><<<256, 256, 0, stream>>>(part, cpA, muF, muT, zsA, out);
    else        k_mufin<false><<<256, 256, 0, stream>>>(part, cpA, muF, muT, zsA, out);
  }
  // new_z with final mu (no mu-update; zB overlays dead part buffer)
  k_em<false, true><<<dim3(NCH, 16), 256, 0, stream>>>(xf, xTf, muF, zB, cpB, part);
  k_attn<<<dim3(32, 16), 256, 0, stream>>>(zB, cpB, out + 262144);
  k_mlp<<<512, 256, 0, stream>>>(zA, muT, zsA, w1bf, w2fr, bnshH, b2, out + 2359296);
}